// Round 2
// baseline (3419.392 us; speedup 1.0000x reference)
//
#include <hip/hip_runtime.h>

#define NPTS 2048
#define BATCH 8
#define KNN 20

// ---------------------------------------------------------------------------
// Transpose FIN(B,N,C) (row stride `stride`, channel offset `off`) -> XT(B,C,N)
__global__ void k_transpose(const float* __restrict__ fin, int stride, int off,
                            float* __restrict__ xt, int C) {
  int i = blockIdx.x * 256 + threadIdx.x;   // linear over B*C*N, n fastest
  int n = i & (NPTS - 1);
  int t = i >> 11;
  int c = t % C;
  int b = t / C;
  xt[i] = fin[(size_t)(b * NPTS + n) * stride + off + c];
}

// sq[b,n] = sum_c XT[b,c,n]^2 (fp32 screen only; exact rescore fixes ranking)
__global__ void k_sqnorm(const float* __restrict__ xt, float* __restrict__ sq, int C) {
  int i = blockIdx.x * 256 + threadIdx.x;   // over B*N
  int b = i >> 11, n = i & (NPTS - 1);
  const float* base = xt + (size_t)b * C * NPTS + n;
  float a = 0.f;
  for (int c = 0; c < C; ++c) { float v = base[(size_t)c * NPTS]; a = fmaf(v, v, a); }
  sq[i] = a;
}

// ---------------------------------------------------------------------------
// Screen: 32 iterative argmax extractions over 2048 cols held in 32 regs/lane.
// col(s) = (s>>2)*256 + wt*4 + (s&3). Writes 32 candidate cols to LDS.
__device__ inline void sel32(float (&d)[32], int wt, int* __restrict__ cand) {
  for (int sel = 0; sel < 32; ++sel) {
    float bv = -1e30f; int bi = 1 << 30;
    #pragma unroll
    for (int s = 0; s < 32; ++s) {
      int col = ((s >> 2) << 8) + (wt << 2) + (s & 3);
      if (d[s] > bv) { bv = d[s]; bi = col; }   // strict > keeps smallest col
    }
    #pragma unroll
    for (int off = 1; off < 64; off <<= 1) {
      float ov = __shfl_xor(bv, off, 64);
      int   oi = __shfl_xor(bi, off, 64);
      if (ov > bv || (ov == bv && oi < bi)) { bv = ov; bi = oi; }
    }
    int osl = ((bi >> 8) << 2) | (bi & 3);
    if (((bi >> 2) & 63) == wt) {
      #pragma unroll
      for (int s = 0; s < 32; ++s) if (s == osl) d[s] = -1e30f;  // static idx only
    }
    if (wt == 0) cand[sel] = bi;
  }
}

// Exact fp64 rescore of the 32 candidates (direct sum-of-squares, no
// cancellation), then pick top-20 by (dist, index) lexicographic min.
__device__ inline void rescore(const float* __restrict__ xb,
                               const float* __restrict__ ctr_row, int C,
                               const int* __restrict__ cand, int wt,
                               int* __restrict__ outp) {
  int m = (wt < 32) ? cand[wt] : 0;
  double dd;
  if (wt < 32) {
    dd = 0.0;
    for (int c = 0; c < C; ++c) {
      double df = (double)ctr_row[c] - (double)xb[(size_t)c * NPTS + m];
      dd = fma(df, df, dd);
    }
  } else {
    dd = 1e300; m = 1 << 30;
  }
  for (int sel = 0; sel < KNN; ++sel) {
    double bv = dd; int bi = m;
    #pragma unroll
    for (int off = 1; off < 64; off <<= 1) {
      double ov = __shfl_xor(bv, off, 64);
      int    oi = __shfl_xor(bi, off, 64);
      if (ov < bv || (ov == bv && oi < bi)) { bv = ov; bi = oi; }
    }
    if (wt == 0) outp[sel] = bi;
    if (m == bi) dd = 1e300;           // owner retires its candidate
  }
}

// Block = 256 thr = 4 waves; each wave owns 2 rows (8 rows/block).
__global__ void __launch_bounds__(256) k_knn(const float* __restrict__ xt,
                                             const float* __restrict__ sq,
                                             int* __restrict__ idxo, int C) {
  __shared__ float ctr[8 * 128];
  __shared__ int cand[8][32];
  int tid = threadIdx.x;
  int b = blockIdx.y;
  int n0 = blockIdx.x * 8;
  for (int i = tid; i < 8 * C; i += 256) {
    int r = i / C, c = i - r * C;
    ctr[r * 128 + c] = xt[((size_t)b * C + c) * NPTS + n0 + r];
  }
  __syncthreads();
  int wave = tid >> 6, wt = tid & 63;
  int r0 = n0 + wave * 2;
  float a0[32], a1[32];
  #pragma unroll
  for (int s = 0; s < 32; ++s) { a0[s] = 0.f; a1[s] = 0.f; }
  const float* xb  = xt + (size_t)b * C * NPTS;
  const float* c0p = ctr + (wave * 2) * 128;
  const float* c1p = c0p + 128;
  for (int c = 0; c < C; ++c) {
    float v0 = c0p[c], v1 = c1p[c];
    const float4* row = (const float4*)(xb + (size_t)c * NPTS) + wt;
    #pragma unroll
    for (int j = 0; j < 8; ++j) {
      float4 xv = row[64 * j];
      a0[j*4+0] = fmaf(v0, xv.x, a0[j*4+0]);
      a0[j*4+1] = fmaf(v0, xv.y, a0[j*4+1]);
      a0[j*4+2] = fmaf(v0, xv.z, a0[j*4+2]);
      a0[j*4+3] = fmaf(v0, xv.w, a0[j*4+3]);
      a1[j*4+0] = fmaf(v1, xv.x, a1[j*4+0]);
      a1[j*4+1] = fmaf(v1, xv.y, a1[j*4+1]);
      a1[j*4+2] = fmaf(v1, xv.z, a1[j*4+2]);
      a1[j*4+3] = fmaf(v1, xv.w, a1[j*4+3]);
    }
  }
  float sqn0 = sq[b * NPTS + r0];
  float sqn1 = sq[b * NPTS + r0 + 1];
  const float4* sqb = (const float4*)(sq + b * NPTS) + wt;
  #pragma unroll
  for (int j = 0; j < 8; ++j) {
    float4 sv = sqb[64 * j];
    a0[j*4+0] = (2.f*a0[j*4+0] - sqn0) - sv.x;
    a0[j*4+1] = (2.f*a0[j*4+1] - sqn0) - sv.y;
    a0[j*4+2] = (2.f*a0[j*4+2] - sqn0) - sv.z;
    a0[j*4+3] = (2.f*a0[j*4+3] - sqn0) - sv.w;
    a1[j*4+0] = (2.f*a1[j*4+0] - sqn1) - sv.x;
    a1[j*4+1] = (2.f*a1[j*4+1] - sqn1) - sv.y;
    a1[j*4+2] = (2.f*a1[j*4+2] - sqn1) - sv.z;
    a1[j*4+3] = (2.f*a1[j*4+3] - sqn1) - sv.w;
  }
  sel32(a0, wt, cand[wave * 2 + 0]);
  sel32(a1, wt, cand[wave * 2 + 1]);
  rescore(xb, c0p, C, cand[wave * 2 + 0], wt, idxo + ((size_t)b * NPTS + r0) * KNN);
  rescore(xb, c1p, C, cand[wave * 2 + 1], wt, idxo + ((size_t)b * NPTS + r0 + 1) * KNN);
}

// ---------------------------------------------------------------------------
// Edge-conv pass1: y[f,k] = w[f,0:C]·(feat_m - ctr) + w[f,C:2C]·ctr, tracking
// max/min over k (BN+leaky monotone per channel; sign(g) picks which) and
// per-channel sum/sumsq (fp64) partials for BN stats.
template <int FPT>
__global__ void __launch_bounds__(64)
k_pass1(const float* __restrict__ fin, int stride, int off, int C, int F,
        const float* __restrict__ w, const int* __restrict__ idxb,
        float* __restrict__ ymax, float* __restrict__ ymin,
        double* __restrict__ stats) {
  __shared__ float ctr[128];
  __shared__ float diff[KNN * 128];
  __shared__ int nidx[KNN];
  int tid = threadIdx.x;
  double csum[FPT], csumsq[FPT];
  #pragma unroll
  for (int i = 0; i < FPT; ++i) { csum[i] = 0.0; csumsq[i] = 0.0; }
  int p0 = blockIdx.x * 8;
  for (int p = 0; p < 8; ++p) {
    int bn = p0 + p;
    int b = bn >> 11;
    __syncthreads();                       // protect LDS from prev iter readers
    if (tid < KNN) nidx[tid] = idxb[bn * KNN + tid];
    for (int c = tid; c < C; c += 64) ctr[c] = fin[(size_t)bn * stride + off + c];
    __syncthreads();
    for (int k = 0; k < KNN; ++k) {
      int m = nidx[k];
      const float* nr = fin + (size_t)((b << 11) + m) * stride + off;
      for (int c = tid; c < C; c += 64) diff[k * C + c] = nr[c] - ctr[c];
    }
    __syncthreads();
    float y0[FPT];
    #pragma unroll
    for (int i = 0; i < FPT; ++i) {
      const float* wr = w + (size_t)(tid + 64 * i) * 2 * C + C;
      float a = 0.f;
      for (int c = 0; c < C; ++c) a = fmaf(wr[c], ctr[c], a);
      y0[i] = a;
    }
    float acc[KNN][FPT];
    #pragma unroll
    for (int k = 0; k < KNN; ++k)
      #pragma unroll
      for (int i = 0; i < FPT; ++i) acc[k][i] = 0.f;
    int C4 = C & ~3;
    for (int c = 0; c < C4; c += 4) {
      float4 wv[FPT];
      #pragma unroll
      for (int i = 0; i < FPT; ++i)
        wv[i] = *(const float4*)(w + (size_t)(tid + 64 * i) * 2 * C + c);
      #pragma unroll
      for (int k = 0; k < KNN; ++k) {
        float4 dv = *(const float4*)&diff[k * C + c];   // broadcast b128 read
        #pragma unroll
        for (int i = 0; i < FPT; ++i) {
          acc[k][i] = fmaf(wv[i].x, dv.x, acc[k][i]);
          acc[k][i] = fmaf(wv[i].y, dv.y, acc[k][i]);
          acc[k][i] = fmaf(wv[i].z, dv.z, acc[k][i]);
          acc[k][i] = fmaf(wv[i].w, dv.w, acc[k][i]);
        }
      }
    }
    for (int c = C4; c < C; ++c) {          // remainder (layer0: C=3)
      float wv[FPT];
      #pragma unroll
      for (int i = 0; i < FPT; ++i) wv[i] = w[(size_t)(tid + 64 * i) * 2 * C + c];
      #pragma unroll
      for (int k = 0; k < KNN; ++k) {
        float dv = diff[k * C + c];
        #pragma unroll
        for (int i = 0; i < FPT; ++i) acc[k][i] = fmaf(wv[i], dv, acc[k][i]);
      }
    }
    #pragma unroll
    for (int i = 0; i < FPT; ++i) {
      float mx = -1e30f, mn = 1e30f;
      double s = 0.0, ss = 0.0;
      #pragma unroll
      for (int k = 0; k < KNN; ++k) {
        float y = y0[i] + acc[k][i];
        mx = fmaxf(mx, y); mn = fminf(mn, y);
        double yd = (double)y;
        s += yd; ss = fma(yd, yd, ss);
      }
      int f = tid + 64 * i;
      ymax[(size_t)bn * F + f] = mx;
      ymin[(size_t)bn * F + f] = mn;
      csum[i] += s; csumsq[i] += ss;
    }
  }
  #pragma unroll
  for (int i = 0; i < FPT; ++i) {
    int f = tid + 64 * i;
    atomicAdd(&stats[f], csum[i]);
    atomicAdd(&stats[F + f], csumsq[i]);
  }
}

// pass2: BN + leaky on the max/min-selected value, write into CAT slice.
__global__ void k_pass2(const float* __restrict__ ymax, const float* __restrict__ ymin,
                        const double* __restrict__ stats, const float* __restrict__ g,
                        const float* __restrict__ bb, float* __restrict__ cat,
                        int Fbits, int catoff) {
  int i = blockIdx.x * 256 + threadIdx.x;   // over B*N*F, f fastest
  int F = 1 << Fbits;
  int f = i & (F - 1);
  int bn = i >> Fbits;
  const double invCnt = 1.0 / (double)(BATCH * NPTS * KNN);
  double mean = stats[f] * invCnt;
  double ex2  = stats[F + f] * invCnt;
  double var  = ex2 - mean * mean;
  if (var < 0.0) var = 0.0;
  double rs   = rsqrt(var + 1e-5);
  float gg = g[f], bv = bb[f];
  float y = (gg >= 0.f) ? ymax[i] : ymin[i];   // sign(scale)=sign(g); g==0 -> const
  float t = (float)((double)gg * ((double)y - mean) * rs + (double)bv);
  cat[(size_t)bn * 512 + catoff + f] = (t >= 0.f) ? t : 0.2f * t;
}

// ---------------------------------------------------------------------------
// Final GEMM: CAT(16384x512) @ wf^T(512x1024) -> out(16384x1024).
__global__ void __launch_bounds__(256) k_gemm(const float* __restrict__ A,
                                              const float* __restrict__ Bw,
                                              float* __restrict__ Cc) {
  __shared__ float As[16][68];
  __shared__ float Bs[16][68];
  int tid = threadIdx.x;
  int m0 = blockIdx.y * 64, f0 = blockIdx.x * 64;
  int ty = tid >> 4, tx = tid & 15;
  int lr = tid >> 2;            // 0..63
  int lk = (tid & 3) * 4;       // 0,4,8,12
  float acc[4][4];
  #pragma unroll
  for (int i = 0; i < 4; ++i)
    #pragma unroll
    for (int j = 0; j < 4; ++j) acc[i][j] = 0.f;
  for (int k0 = 0; k0 < 512; k0 += 16) {
    float4 av = *(const float4*)&A [(size_t)(m0 + lr) * 512 + k0 + lk];
    float4 bv = *(const float4*)&Bw[(size_t)(f0 + lr) * 512 + k0 + lk];
    __syncthreads();
    As[lk+0][lr] = av.x; As[lk+1][lr] = av.y; As[lk+2][lr] = av.z; As[lk+3][lr] = av.w;
    Bs[lk+0][lr] = bv.x; Bs[lk+1][lr] = bv.y; Bs[lk+2][lr] = bv.z; Bs[lk+3][lr] = bv.w;
    __syncthreads();
    #pragma unroll
    for (int kk = 0; kk < 16; ++kk) {
      float4 a = *(const float4*)&As[kk][ty * 4];
      float4 b = *(const float4*)&Bs[kk][tx * 4];
      acc[0][0] = fmaf(a.x, b.x, acc[0][0]); acc[0][1] = fmaf(a.x, b.y, acc[0][1]);
      acc[0][2] = fmaf(a.x, b.z, acc[0][2]); acc[0][3] = fmaf(a.x, b.w, acc[0][3]);
      acc[1][0] = fmaf(a.y, b.x, acc[1][0]); acc[1][1] = fmaf(a.y, b.y, acc[1][1]);
      acc[1][2] = fmaf(a.y, b.z, acc[1][2]); acc[1][3] = fmaf(a.y, b.w, acc[1][3]);
      acc[2][0] = fmaf(a.z, b.x, acc[2][0]); acc[2][1] = fmaf(a.z, b.y, acc[2][1]);
      acc[2][2] = fmaf(a.z, b.z, acc[2][2]); acc[2][3] = fmaf(a.z, b.w, acc[2][3]);
      acc[3][0] = fmaf(a.w, b.x, acc[3][0]); acc[3][1] = fmaf(a.w, b.y, acc[3][1]);
      acc[3][2] = fmaf(a.w, b.z, acc[3][2]); acc[3][3] = fmaf(a.w, b.w, acc[3][3]);
    }
  }
  #pragma unroll
  for (int i = 0; i < 4; ++i)
    #pragma unroll
    for (int j = 0; j < 4; ++j)
      Cc[(size_t)(m0 + ty * 4 + i) * 1024 + f0 + tx * 4 + j] = acc[i][j];
}

// Per-channel sum/sumsq (fp64) over 16384 rows of out(16384x1024).
__global__ void k_fstats(const float* __restrict__ y, double* __restrict__ st) {
  int tid = threadIdx.x;
  int r0 = blockIdx.x * 256;
  double s[4] = {0,0,0,0}, ss[4] = {0,0,0,0};
  for (int r = r0; r < r0 + 256; ++r) {
    const float* row = y + (size_t)r * 1024;
    #pragma unroll
    for (int q = 0; q < 4; ++q) {
      double v = (double)row[tid + 256 * q];
      s[q] += v; ss[q] = fma(v, v, ss[q]);
    }
  }
  #pragma unroll
  for (int q = 0; q < 4; ++q) {
    atomicAdd(&st[tid + 256 * q], s[q]);
    atomicAdd(&st[1024 + tid + 256 * q], ss[q]);
  }
}

__global__ void k_fnorm(float* __restrict__ y, const double* __restrict__ st,
                        const float* __restrict__ g, const float* __restrict__ bb) {
  int i = blockIdx.x * 256 + threadIdx.x;
  int f = i & 1023;
  const double invCnt = 1.0 / 16384.0;
  double mean = st[f] * invCnt;
  double ex2  = st[1024 + f] * invCnt;
  double var  = ex2 - mean * mean;
  if (var < 0.0) var = 0.0;
  double rs   = rsqrt(var + 1e-5);
  float v = y[i];
  float t = (float)((double)g[f] * ((double)v - mean) * rs + (double)bb[f]);
  y[i] = (t >= 0.f) ? t : 0.2f * t;
}

// ---------------------------------------------------------------------------
extern "C" void kernel_launch(void* const* d_in, const int* in_sizes, int n_in,
                              void* d_out, int out_size, void* d_ws, size_t ws_size,
                              hipStream_t stream) {
  const float* x  = (const float*)d_in[0];
  const float* W[4]  = {(const float*)d_in[1], (const float*)d_in[4],
                        (const float*)d_in[7], (const float*)d_in[10]};
  const float* G[4]  = {(const float*)d_in[2], (const float*)d_in[5],
                        (const float*)d_in[8], (const float*)d_in[11]};
  const float* Bb[4] = {(const float*)d_in[3], (const float*)d_in[6],
                        (const float*)d_in[9], (const float*)d_in[12]};
  const float* wf = (const float*)d_in[13];
  const float* gf = (const float*)d_in[14];
  const float* bf = (const float*)d_in[15];
  float* out = (float*)d_out;

  // workspace carve: ~77 MB total
  float* ws  = (float*)d_ws;
  float* XT  = ws;                 // 8*128*2048      = 2,097,152 f
  float* SQ  = XT + 2097152;       // 8*2048          =    16,384 f
  float* YMX = SQ + 16384;         // 16384*256       = 4,194,304 f
  float* YMN = YMX + 4194304;      //                 = 4,194,304 f
  float* CAT = YMN + 4194304;      // 16384*512       = 8,388,608 f
  double* ST = (double*)(CAT + 8388608);   // 2048 doubles (byte off mult of 8)
  int*   IDX = (int*)(ST + 2048);  // 16384*20 ints

  const int Cs[4]      = {3, 64, 64, 128};
  const int Fs[4]      = {64, 64, 128, 256};
  const int Fbits[4]   = {6, 6, 7, 8};
  const int fpts[4]    = {1, 1, 2, 4};
  const int offs[4]    = {0, 0, 64, 128};
  const int strides[4] = {3, 512, 512, 512};
  const int catoffs[4] = {0, 64, 128, 256};

  for (int l = 0; l < 4; ++l) {
    const float* fin = (l == 0) ? x : CAT;
    int C = Cs[l], F = Fs[l];
    k_transpose<<<dim3(BATCH * C * NPTS / 256), 256, 0, stream>>>(fin, strides[l], offs[l], XT, C);
    k_sqnorm<<<dim3(BATCH * NPTS / 256), 256, 0, stream>>>(XT, SQ, C);
    k_knn<<<dim3(NPTS / 8, BATCH), 256, 0, stream>>>(XT, SQ, IDX, C);
    (void)hipMemsetAsync(ST, 0, 2 * F * sizeof(double), stream);
    switch (fpts[l]) {
      case 1: k_pass1<1><<<dim3(BATCH * NPTS / 8), 64, 0, stream>>>(fin, strides[l], offs[l], C, F, W[l], IDX, YMX, YMN, ST); break;
      case 2: k_pass1<2><<<dim3(BATCH * NPTS / 8), 64, 0, stream>>>(fin, strides[l], offs[l], C, F, W[l], IDX, YMX, YMN, ST); break;
      default: k_pass1<4><<<dim3(BATCH * NPTS / 8), 64, 0, stream>>>(fin, strides[l], offs[l], C, F, W[l], IDX, YMX, YMN, ST); break;
    }
    k_pass2<<<dim3(BATCH * NPTS * F / 256), 256, 0, stream>>>(YMX, YMN, ST, G[l], Bb[l], CAT, Fbits[l], catoffs[l]);
  }

  k_gemm<<<dim3(1024 / 64, 16384 / 64), 256, 0, stream>>>(CAT, wf, out);
  (void)hipMemsetAsync(ST, 0, 2048 * sizeof(double), stream);
  k_fstats<<<dim3(64), 256, 0, stream>>>(out, ST);
  k_fnorm<<<dim3(16384 * 1024 / 256), 256, 0, stream>>>(out, ST, gf, bf);
}

// Round 3
// 3204.539 us; speedup vs baseline: 1.0670x; 1.0670x over previous
//
#include <hip/hip_runtime.h>

#define NPTS 2048
#define BATCH 8
#define KNN 20

// ---------------------------------------------------------------------------
// Transpose FIN(B,N,C) (row stride `stride`, channel offset `off`) -> XT(B,C,N)
__global__ void k_transpose(const float* __restrict__ fin, int stride, int off,
                            float* __restrict__ xt, int C) {
  int i = blockIdx.x * 256 + threadIdx.x;   // linear over B*C*N, n fastest
  int n = i & (NPTS - 1);
  int t = i >> 11;
  int c = t % C;
  int b = t / C;
  xt[i] = fin[(size_t)(b * NPTS + n) * stride + off + c];
}

// sq[b,n] = sum_c XT[b,c,n]^2 (fp32 screen only; exact rescore fixes ranking)
__global__ void k_sqnorm(const float* __restrict__ xt, float* __restrict__ sq, int C) {
  int i = blockIdx.x * 256 + threadIdx.x;   // over B*N
  int b = i >> 11, n = i & (NPTS - 1);
  const float* base = xt + (size_t)b * C * NPTS + n;
  float a = 0.f;
  for (int c = 0; c < C; ++c) { float v = base[(size_t)c * NPTS]; a = fmaf(v, v, a); }
  sq[i] = a;
}

// ---------------------------------------------------------------------------
// Screen: 32 iterative argmax extractions over 2048 cols held in 32 regs/lane.
// col(s) = (s>>2)*256 + wt*4 + (s&3). Writes 32 candidate cols to LDS.
__device__ inline void sel32(float (&d)[32], int wt, int* __restrict__ cand) {
  for (int sel = 0; sel < 32; ++sel) {
    float bv = -1e30f; int bi = 1 << 30;
    #pragma unroll
    for (int s = 0; s < 32; ++s) {
      int col = ((s >> 2) << 8) + (wt << 2) + (s & 3);
      if (d[s] > bv) { bv = d[s]; bi = col; }   // strict > keeps smallest col
    }
    #pragma unroll
    for (int off = 1; off < 64; off <<= 1) {
      float ov = __shfl_xor(bv, off, 64);
      int   oi = __shfl_xor(bi, off, 64);
      if (ov > bv || (ov == bv && oi < bi)) { bv = ov; bi = oi; }
    }
    int osl = ((bi >> 8) << 2) | (bi & 3);
    if (((bi >> 2) & 63) == wt) {
      #pragma unroll
      for (int s = 0; s < 32; ++s) if (s == osl) d[s] = -1e30f;  // static idx only
    }
    if (wt == 0) cand[sel] = bi;
  }
}

// Exact fp64 rescore of the 32 candidates (direct sum-of-squares, no
// cancellation), then pick top-20 by (dist, index) lexicographic min.
__device__ inline void rescore(const float* __restrict__ xb,
                               const float* __restrict__ ctr_row, int C,
                               const int* __restrict__ cand, int wt,
                               int* __restrict__ outp) {
  int m = (wt < 32) ? cand[wt] : 0;
  double dd;
  if (wt < 32) {
    dd = 0.0;
    for (int c = 0; c < C; ++c) {
      double df = (double)ctr_row[c] - (double)xb[(size_t)c * NPTS + m];
      dd = fma(df, df, dd);
    }
  } else {
    dd = 1e300; m = 1 << 30;
  }
  for (int sel = 0; sel < KNN; ++sel) {
    double bv = dd; int bi = m;
    #pragma unroll
    for (int off = 1; off < 64; off <<= 1) {
      double ov = __shfl_xor(bv, off, 64);
      int    oi = __shfl_xor(bi, off, 64);
      if (ov < bv || (ov == bv && oi < bi)) { bv = ov; bi = oi; }
    }
    if (wt == 0) outp[sel] = bi;
    if (m == bi) dd = 1e300;           // owner retires its candidate
  }
}

// Block = 256 thr = 4 waves; each wave owns 2 rows (8 rows/block).
__global__ void __launch_bounds__(256) k_knn(const float* __restrict__ xt,
                                             const float* __restrict__ sq,
                                             int* __restrict__ idxo, int C) {
  __shared__ float ctr[8 * 128];
  __shared__ int cand[8][32];
  int tid = threadIdx.x;
  int b = blockIdx.y;
  int n0 = blockIdx.x * 8;
  for (int i = tid; i < 8 * C; i += 256) {
    int r = i / C, c = i - r * C;
    ctr[r * 128 + c] = xt[((size_t)b * C + c) * NPTS + n0 + r];
  }
  __syncthreads();
  int wave = tid >> 6, wt = tid & 63;
  int r0 = n0 + wave * 2;
  float a0[32], a1[32];
  #pragma unroll
  for (int s = 0; s < 32; ++s) { a0[s] = 0.f; a1[s] = 0.f; }
  const float* xb  = xt + (size_t)b * C * NPTS;
  const float* c0p = ctr + (wave * 2) * 128;
  const float* c1p = c0p + 128;
  for (int c = 0; c < C; ++c) {
    float v0 = c0p[c], v1 = c1p[c];
    const float4* row = (const float4*)(xb + (size_t)c * NPTS) + wt;
    #pragma unroll
    for (int j = 0; j < 8; ++j) {
      float4 xv = row[64 * j];
      a0[j*4+0] = fmaf(v0, xv.x, a0[j*4+0]);
      a0[j*4+1] = fmaf(v0, xv.y, a0[j*4+1]);
      a0[j*4+2] = fmaf(v0, xv.z, a0[j*4+2]);
      a0[j*4+3] = fmaf(v0, xv.w, a0[j*4+3]);
      a1[j*4+0] = fmaf(v1, xv.x, a1[j*4+0]);
      a1[j*4+1] = fmaf(v1, xv.y, a1[j*4+1]);
      a1[j*4+2] = fmaf(v1, xv.z, a1[j*4+2]);
      a1[j*4+3] = fmaf(v1, xv.w, a1[j*4+3]);
    }
  }
  float sqn0 = sq[b * NPTS + r0];
  float sqn1 = sq[b * NPTS + r0 + 1];
  const float4* sqb = (const float4*)(sq + b * NPTS) + wt;
  #pragma unroll
  for (int j = 0; j < 8; ++j) {
    float4 sv = sqb[64 * j];
    a0[j*4+0] = (2.f*a0[j*4+0] - sqn0) - sv.x;
    a0[j*4+1] = (2.f*a0[j*4+1] - sqn0) - sv.y;
    a0[j*4+2] = (2.f*a0[j*4+2] - sqn0) - sv.z;
    a0[j*4+3] = (2.f*a0[j*4+3] - sqn0) - sv.w;
    a1[j*4+0] = (2.f*a1[j*4+0] - sqn1) - sv.x;
    a1[j*4+1] = (2.f*a1[j*4+1] - sqn1) - sv.y;
    a1[j*4+2] = (2.f*a1[j*4+2] - sqn1) - sv.z;
    a1[j*4+3] = (2.f*a1[j*4+3] - sqn1) - sv.w;
  }
  sel32(a0, wt, cand[wave * 2 + 0]);
  sel32(a1, wt, cand[wave * 2 + 1]);
  rescore(xb, c0p, C, cand[wave * 2 + 0], wt, idxo + ((size_t)b * NPTS + r0) * KNN);
  rescore(xb, c1p, C, cand[wave * 2 + 1], wt, idxo + ((size_t)b * NPTS + r0 + 1) * KNN);
}

// ---------------------------------------------------------------------------
// Edge-conv via Z/T decomposition:
//   y[n,k,f] = w1[f]·x_{m(n,k)} + (w2−w1)[f]·x_n = Z[m,f] + T[n,f]
// One GEMM produces [Z | T] = X @ WC^T with WC = [w1; w2−w1] (2F rows).

// WC prep: rows 0..F-1 = w1 = w[f][0:C]; rows F..2F-1 = w[f][C:2C]-w[f][0:C]
__global__ void k_wprep(const float* __restrict__ w, float* __restrict__ wc,
                        int C, int F) {
  int i = blockIdx.x * 256 + threadIdx.x;
  if (i >= 2 * F * C) return;
  int n = i / C, c = i - n * C;
  wc[i] = (n < F) ? w[(size_t)n * 2 * C + c]
                  : w[(size_t)(n - F) * 2 * C + C + c] - w[(size_t)(n - F) * 2 * C + c];
}

// ZT(16384 x W2F) = A(16384 x C; row stride lda, col offset off) @ WC^T
// 64x64 tile, full-K resident in LDS (C<=128), 4x4 microtile.
template <int C>
__global__ void __launch_bounds__(256) k_zgemm(const float* __restrict__ A, int lda, int off,
                                               const float* __restrict__ WC, int W2F,
                                               float* __restrict__ ZT) {
  __shared__ float As[C][68];
  __shared__ float Ws[C][68];
  int tid = threadIdx.x;
  int m0 = blockIdx.y * 64, f0 = blockIdx.x * 64;
  for (int i = tid; i < 64 * C; i += 256) {
    int r = i / C, c = i - r * C;
    As[c][r] = A[(size_t)(m0 + r) * lda + off + c];
    Ws[c][r] = WC[(size_t)(f0 + r) * C + c];
  }
  __syncthreads();
  int ty = tid >> 4, tx = tid & 15;
  float acc[4][4];
  #pragma unroll
  for (int i = 0; i < 4; ++i)
    #pragma unroll
    for (int j = 0; j < 4; ++j) acc[i][j] = 0.f;
  for (int kk = 0; kk < C; ++kk) {
    float4 a = *(const float4*)&As[kk][ty * 4];
    float4 b = *(const float4*)&Ws[kk][tx * 4];
    acc[0][0] = fmaf(a.x, b.x, acc[0][0]); acc[0][1] = fmaf(a.x, b.y, acc[0][1]);
    acc[0][2] = fmaf(a.x, b.z, acc[0][2]); acc[0][3] = fmaf(a.x, b.w, acc[0][3]);
    acc[1][0] = fmaf(a.y, b.x, acc[1][0]); acc[1][1] = fmaf(a.y, b.y, acc[1][1]);
    acc[1][2] = fmaf(a.y, b.z, acc[1][2]); acc[1][3] = fmaf(a.y, b.w, acc[1][3]);
    acc[2][0] = fmaf(a.z, b.x, acc[2][0]); acc[2][1] = fmaf(a.z, b.y, acc[2][1]);
    acc[2][2] = fmaf(a.z, b.z, acc[2][2]); acc[2][3] = fmaf(a.z, b.w, acc[2][3]);
    acc[3][0] = fmaf(a.w, b.x, acc[3][0]); acc[3][1] = fmaf(a.w, b.y, acc[3][1]);
    acc[3][2] = fmaf(a.w, b.z, acc[3][2]); acc[3][3] = fmaf(a.w, b.w, acc[3][3]);
  }
  #pragma unroll
  for (int i = 0; i < 4; ++i)
    #pragma unroll
    for (int j = 0; j < 4; ++j)
      ZT[(size_t)(m0 + ty * 4 + i) * W2F + f0 + tx * 4 + j] = acc[i][j];
}

// Gather-reduce: per (n,f) compute max/min over k of Z[m_k,f]+T[n,f], select
// by sign(g[f]) (BN+leaky monotone), write pre-BN value into CAT slice, and
// accumulate fp64 sum/sumsq partials for BN stats.
// Block = 256 = PL point-lanes x F channels; SP points serial per lane.
template <int F, int PL, int SP>
__global__ void __launch_bounds__(256) k_gather(const float* __restrict__ ZT, int W2F,
                                                const int* __restrict__ idxb,
                                                const float* __restrict__ g,
                                                float* __restrict__ cat, int catoff,
                                                double* __restrict__ stats) {
  int tid = threadIdx.x;
  int pl = tid / F, f = tid & (F - 1);
  float gg = g[f];
  double s = 0.0, ss = 0.0;
  int nbase = blockIdx.x * (PL * SP) + pl * SP;
  for (int sp = 0; sp < SP; ++sp) {
    int n = nbase + sp;
    int gbase = n & ~(NPTS - 1);
    const int* ip = idxb + n * KNN;
    float T = ZT[(size_t)n * W2F + F + f];
    float mx = -1e30f, mn = 1e30f;
    #pragma unroll
    for (int k = 0; k < KNN; ++k) {
      int m = ip[k];
      float z = ZT[(size_t)(gbase + m) * W2F + f];
      float y = z + T;
      mx = fmaxf(mx, y); mn = fminf(mn, y);
      double yd = (double)y;
      s += yd; ss = fma(yd, yd, ss);
    }
    cat[(size_t)n * 512 + catoff + f] = (gg >= 0.f) ? mx : mn;
  }
  atomicAdd(&stats[f], s);
  atomicAdd(&stats[F + f], ss);
}

// BN + leaky, in place on the CAT slice.
__global__ void k_bn(float* __restrict__ cat, const double* __restrict__ stats,
                     const float* __restrict__ g, const float* __restrict__ bb,
                     int Fbits, int catoff) {
  int i = blockIdx.x * 256 + threadIdx.x;   // over B*N*F, f fastest
  int F = 1 << Fbits;
  int f = i & (F - 1);
  int bn = i >> Fbits;
  const double invCnt = 1.0 / (double)(BATCH * NPTS * KNN);
  double mean = stats[f] * invCnt;
  double ex2  = stats[F + f] * invCnt;
  double var  = ex2 - mean * mean;
  if (var < 0.0) var = 0.0;
  double rs   = rsqrt(var + 1e-5);
  float* p = &cat[(size_t)bn * 512 + catoff + f];
  float y = *p;
  float t = (float)((double)g[f] * ((double)y - mean) * rs + (double)bb[f]);
  *p = (t >= 0.f) ? t : 0.2f * t;
}

// ---------------------------------------------------------------------------
// Final GEMM: CAT(16384x512) @ wf^T(512x1024) -> out(16384x1024).
__global__ void __launch_bounds__(256) k_gemm(const float* __restrict__ A,
                                              const float* __restrict__ Bw,
                                              float* __restrict__ Cc) {
  __shared__ float As[16][68];
  __shared__ float Bs[16][68];
  int tid = threadIdx.x;
  int m0 = blockIdx.y * 64, f0 = blockIdx.x * 64;
  int ty = tid >> 4, tx = tid & 15;
  int lr = tid >> 2;            // 0..63
  int lk = (tid & 3) * 4;       // 0,4,8,12
  float acc[4][4];
  #pragma unroll
  for (int i = 0; i < 4; ++i)
    #pragma unroll
    for (int j = 0; j < 4; ++j) acc[i][j] = 0.f;
  for (int k0 = 0; k0 < 512; k0 += 16) {
    float4 av = *(const float4*)&A [(size_t)(m0 + lr) * 512 + k0 + lk];
    float4 bv = *(const float4*)&Bw[(size_t)(f0 + lr) * 512 + k0 + lk];
    __syncthreads();
    As[lk+0][lr] = av.x; As[lk+1][lr] = av.y; As[lk+2][lr] = av.z; As[lk+3][lr] = av.w;
    Bs[lk+0][lr] = bv.x; Bs[lk+1][lr] = bv.y; Bs[lk+2][lr] = bv.z; Bs[lk+3][lr] = bv.w;
    __syncthreads();
    #pragma unroll
    for (int kk = 0; kk < 16; ++kk) {
      float4 a = *(const float4*)&As[kk][ty * 4];
      float4 b = *(const float4*)&Bs[kk][tx * 4];
      acc[0][0] = fmaf(a.x, b.x, acc[0][0]); acc[0][1] = fmaf(a.x, b.y, acc[0][1]);
      acc[0][2] = fmaf(a.x, b.z, acc[0][2]); acc[0][3] = fmaf(a.x, b.w, acc[0][3]);
      acc[1][0] = fmaf(a.y, b.x, acc[1][0]); acc[1][1] = fmaf(a.y, b.y, acc[1][1]);
      acc[1][2] = fmaf(a.y, b.z, acc[1][2]); acc[1][3] = fmaf(a.y, b.w, acc[1][3]);
      acc[2][0] = fmaf(a.z, b.x, acc[2][0]); acc[2][1] = fmaf(a.z, b.y, acc[2][1]);
      acc[2][2] = fmaf(a.z, b.z, acc[2][2]); acc[2][3] = fmaf(a.z, b.w, acc[2][3]);
      acc[3][0] = fmaf(a.w, b.x, acc[3][0]); acc[3][1] = fmaf(a.w, b.y, acc[3][1]);
      acc[3][2] = fmaf(a.w, b.z, acc[3][2]); acc[3][3] = fmaf(a.w, b.w, acc[3][3]);
    }
  }
  #pragma unroll
  for (int i = 0; i < 4; ++i)
    #pragma unroll
    for (int j = 0; j < 4; ++j)
      Cc[(size_t)(m0 + ty * 4 + i) * 1024 + f0 + tx * 4 + j] = acc[i][j];
}

// Per-channel sum/sumsq (fp64) over 16384 rows of out(16384x1024).
__global__ void k_fstats(const float* __restrict__ y, double* __restrict__ st) {
  int tid = threadIdx.x;
  int r0 = blockIdx.x * 256;
  double s[4] = {0,0,0,0}, ss[4] = {0,0,0,0};
  for (int r = r0; r < r0 + 256; ++r) {
    const float* row = y + (size_t)r * 1024;
    #pragma unroll
    for (int q = 0; q < 4; ++q) {
      double v = (double)row[tid + 256 * q];
      s[q] += v; ss[q] = fma(v, v, ss[q]);
    }
  }
  #pragma unroll
  for (int q = 0; q < 4; ++q) {
    atomicAdd(&st[tid + 256 * q], s[q]);
    atomicAdd(&st[1024 + tid + 256 * q], ss[q]);
  }
}

__global__ void k_fnorm(float* __restrict__ y, const double* __restrict__ st,
                        const float* __restrict__ g, const float* __restrict__ bb) {
  int i = blockIdx.x * 256 + threadIdx.x;
  int f = i & 1023;
  const double invCnt = 1.0 / 16384.0;
  double mean = st[f] * invCnt;
  double ex2  = st[1024 + f] * invCnt;
  double var  = ex2 - mean * mean;
  if (var < 0.0) var = 0.0;
  double rs   = rsqrt(var + 1e-5);
  float v = y[i];
  float t = (float)((double)g[f] * ((double)v - mean) * rs + (double)bb[f]);
  y[i] = (t >= 0.f) ? t : 0.2f * t;
}

// ---------------------------------------------------------------------------
extern "C" void kernel_launch(void* const* d_in, const int* in_sizes, int n_in,
                              void* d_out, int out_size, void* d_ws, size_t ws_size,
                              hipStream_t stream) {
  const float* x  = (const float*)d_in[0];
  const float* W[4]  = {(const float*)d_in[1], (const float*)d_in[4],
                        (const float*)d_in[7], (const float*)d_in[10]};
  const float* G[4]  = {(const float*)d_in[2], (const float*)d_in[5],
                        (const float*)d_in[8], (const float*)d_in[11]};
  const float* Bb[4] = {(const float*)d_in[3], (const float*)d_in[6],
                        (const float*)d_in[9], (const float*)d_in[12]};
  const float* wf = (const float*)d_in[13];
  const float* gf = (const float*)d_in[14];
  const float* bf = (const float*)d_in[15];
  float* out = (float*)d_out;

  // workspace carve: ~77 MB
  float* ws  = (float*)d_ws;
  float* XT  = ws;                 // 8*128*2048      = 2,097,152 f
  float* SQ  = XT + 2097152;       // 8*2048          =    16,384 f
  float* CAT = SQ + 16384;         // 16384*512       = 8,388,608 f
  float* ZT  = CAT + 8388608;      // 16384*512       = 8,388,608 f
  float* WC  = ZT + 8388608;       // 512*128 max     =    65,536 f
  double* ST = (double*)(WC + 65536);      // 2048 doubles
  int*   IDX = (int*)(ST + 2048);  // 16384*20 ints

  const int Cs[4]      = {3, 64, 64, 128};
  const int Fs[4]      = {64, 64, 128, 256};
  const int Fbits[4]   = {6, 6, 7, 8};
  const int offs[4]    = {0, 0, 64, 128};
  const int strides[4] = {3, 512, 512, 512};
  const int catoffs[4] = {0, 64, 128, 256};

  for (int l = 0; l < 4; ++l) {
    const float* fin = (l == 0) ? x : CAT;
    int C = Cs[l], F = Fs[l];
    int W2F = 2 * F;
    k_transpose<<<dim3(BATCH * C * NPTS / 256), 256, 0, stream>>>(fin, strides[l], offs[l], XT, C);
    k_sqnorm<<<dim3(BATCH * NPTS / 256), 256, 0, stream>>>(XT, SQ, C);
    k_knn<<<dim3(NPTS / 8, BATCH), 256, 0, stream>>>(XT, SQ, IDX, C);
    k_wprep<<<dim3((2 * F * C + 255) / 256), 256, 0, stream>>>(W[l], WC, C, F);
    switch (C) {
      case 3:   k_zgemm<3>  <<<dim3(W2F / 64, 256), 256, 0, stream>>>(fin, strides[l], offs[l], WC, W2F, ZT); break;
      case 64:  k_zgemm<64> <<<dim3(W2F / 64, 256), 256, 0, stream>>>(fin, strides[l], offs[l], WC, W2F, ZT); break;
      default:  k_zgemm<128><<<dim3(W2F / 64, 256), 256, 0, stream>>>(fin, strides[l], offs[l], WC, W2F, ZT); break;
    }
    (void)hipMemsetAsync(ST, 0, 2 * F * sizeof(double), stream);
    switch (F) {
      case 64:  k_gather<64, 4, 16><<<dim3(16384 / 64), 256, 0, stream>>>(ZT, W2F, IDX, G[l], CAT, catoffs[l], ST); break;
      case 128: k_gather<128, 2, 16><<<dim3(16384 / 32), 256, 0, stream>>>(ZT, W2F, IDX, G[l], CAT, catoffs[l], ST); break;
      default:  k_gather<256, 1, 16><<<dim3(16384 / 16), 256, 0, stream>>>(ZT, W2F, IDX, G[l], CAT, catoffs[l], ST); break;
    }
    k_bn<<<dim3(BATCH * NPTS * F / 256), 256, 0, stream>>>(CAT, ST, G[l], Bb[l], Fbits[l], catoffs[l]);
  }

  k_gemm<<<dim3(1024 / 64, 16384 / 64), 256, 0, stream>>>(CAT, wf, out);
  (void)hipMemsetAsync(ST, 0, 2048 * sizeof(double), stream);
  k_fstats<<<dim3(64), 256, 0, stream>>>(out, ST);
  k_fnorm<<<dim3(16384 * 1024 / 256), 256, 0, stream>>>(out, ST, gf, bf);
}

// Round 4
// 1685.771 us; speedup vs baseline: 2.0284x; 1.9009x over previous
//
#include <hip/hip_runtime.h>

#define NPTS 2048
#define BATCH 8
#define KNN 20

// ---------------------------------------------------------------------------
// Transpose FIN(B,N,C) (row stride `stride`, channel offset `off`) -> XT(B,C,N)
__global__ void k_transpose(const float* __restrict__ fin, int stride, int off,
                            float* __restrict__ xt, int C) {
  int i = blockIdx.x * 256 + threadIdx.x;   // linear over B*C*N, n fastest
  int n = i & (NPTS - 1);
  int t = i >> 11;
  int c = t % C;
  int b = t / C;
  xt[i] = fin[(size_t)(b * NPTS + n) * stride + off + c];
}

// sq[b,n] = sum_c XT[b,c,n]^2 (fp32 screen only; exact rescore fixes ranking)
__global__ void k_sqnorm(const float* __restrict__ xt, float* __restrict__ sq, int C) {
  int i = blockIdx.x * 256 + threadIdx.x;   // over B*N
  int b = i >> 11, n = i & (NPTS - 1);
  const float* base = xt + (size_t)b * C * NPTS + n;
  float a = 0.f;
  for (int c = 0; c < C; ++c) { float v = base[(size_t)c * NPTS]; a = fmaf(v, v, a); }
  sq[i] = a;
}

// ---------------------------------------------------------------------------
// Order-preserving float->uint map (monotone increasing).
__device__ inline unsigned f2u(float f) {
  unsigned b = __float_as_uint(f);
  return b ^ (unsigned)(((int)b >> 31) | 0x80000000);
}

// Per-row selection: 3-level radix threshold for the top-32 screened values,
// compact candidates (>= 24-bit threshold prefix, cap 64), exact fp64 rescore
// from row-major fin, rank-by-count -> top-20 (dist asc, index asc).
// All LDS regions are wave-private; only wave-level fences needed.
__device__ inline void row_select(const float (&dv)[32], int wt,
                                  unsigned* __restrict__ hist,   // [256]
                                  unsigned* __restrict__ cntp,   // [1]
                                  int*      __restrict__ candc,  // [64]
                                  double*   __restrict__ candd,  // [64]
                                  const float* __restrict__ ctrrow,
                                  const float* __restrict__ finb, // + b*2048*stride
                                  int stride, int off, int C,
                                  int* __restrict__ outp) {
  unsigned u[32];
  #pragma unroll
  for (int s = 0; s < 32; ++s) u[s] = f2u(dv[s]);

  unsigned K = 32;        // rank target within current prefix class
  unsigned pbits = 0;     // selected prefix bits (positioned)
  unsigned maskhi = 0;    // mask of refined bits
  for (int lvl = 0; lvl < 3; ++lvl) {
    int sh = 24 - 8 * lvl;
    #pragma unroll
    for (int j = 0; j < 4; ++j) hist[wt * 4 + j] = 0u;
    __threadfence_block();
    #pragma unroll
    for (int s = 0; s < 32; ++s) {
      unsigned uu = u[s];
      if ((uu & maskhi) == pbits) atomicAdd(&hist[(uu >> sh) & 255u], 1u);
    }
    __threadfence_block();
    unsigned h[4];
    #pragma unroll
    for (int j = 0; j < 4; ++j) h[j] = hist[wt * 4 + j];
    unsigned lsum = h[0] + h[1] + h[2] + h[3];
    unsigned acc = lsum;
    #pragma unroll
    for (int o = 1; o < 64; o <<= 1) {       // inclusive suffix sum over lanes
      unsigned t = __shfl_down(acc, o, 64);
      acc += (wt + o < 64) ? t : 0u;
    }
    unsigned S = acc - lsum;                 // sum over strictly-higher lanes
    unsigned ca3 = S;
    unsigned ca2 = ca3 + h[3];
    unsigned ca1 = ca2 + h[2];
    unsigned ca0 = ca1 + h[1];
    unsigned ca[4] = {ca0, ca1, ca2, ca3};
    int myb = -1; unsigned myK = 0;
    #pragma unroll
    for (int j = 3; j >= 0; --j)
      if (myb < 0 && ca[j] < K && K <= ca[j] + h[j]) { myb = 4 * wt + j; myK = K - ca[j]; }
    unsigned long long mk = __ballot(myb >= 0);
    int src = __ffsll((unsigned long long)mk) - 1;
    int B = __shfl(myb, src, 64);
    K = (unsigned)__shfl((int)myK, src, 64);
    pbits |= ((unsigned)B & 255u) << sh;
    maskhi |= 255u << sh;
  }
  unsigned T = pbits;                        // low byte zero: superset threshold

  if (wt == 0) *cntp = 0u;
  __threadfence_block();
  #pragma unroll
  for (int s = 0; s < 32; ++s) {
    if (u[s] >= T) {
      unsigned pos = atomicAdd(cntp, 1u);
      if (pos < 64u) candc[pos] = ((s >> 2) << 8) + (wt << 2) + (s & 3);
    }
  }
  __threadfence_block();
  int cnt = (int)min(*cntp, 64u);            // >=32 by construction

  // exact fp64 rescore (sequential ascending-c fma — numerics as before)
  int m; double dd;
  if (wt < cnt) {
    m = candc[wt];
    dd = 0.0;
    const float* nr = finb + (size_t)m * stride + off;
    int C4 = C & ~3;
    for (int c = 0; c < C4; c += 4) {
      float4 xv = *(const float4*)(nr + c);
      double d0 = (double)ctrrow[c + 0] - (double)xv.x;
      dd = fma(d0, d0, dd);
      double d1 = (double)ctrrow[c + 1] - (double)xv.y;
      dd = fma(d1, d1, dd);
      double d2 = (double)ctrrow[c + 2] - (double)xv.z;
      dd = fma(d2, d2, dd);
      double d3 = (double)ctrrow[c + 3] - (double)xv.w;
      dd = fma(d3, d3, dd);
    }
    for (int c = C4; c < C; ++c) {
      double df = (double)ctrrow[c] - (double)nr[c];
      dd = fma(df, df, dd);
    }
  } else { dd = 1e300; m = 1 << 30; }
  candd[wt] = dd;
  __threadfence_block();

  // rank = #{j: (dd_j, m_j) < (dd, m)}; ranks distinct (m unique per cand)
  int rank = 0;
  for (int j = 0; j < cnt; ++j) {
    double dj = candd[j]; int mj = candc[j];
    rank += (dj < dd || (dj == dd && mj < m)) ? 1 : 0;
  }
  if (wt < cnt && rank < KNN) outp[rank] = m;
}

// Block = 256 thr = 4 waves; each wave owns 2 rows (8 rows/block).
__global__ void __launch_bounds__(256) k_knn(const float* __restrict__ xt,
                                             const float* __restrict__ sq,
                                             const float* __restrict__ fin,
                                             int stride, int off,
                                             int* __restrict__ idxo, int C) {
  __shared__ float ctr[8 * 128];
  __shared__ unsigned histS[4][256];
  __shared__ unsigned cntS[4];
  __shared__ int candcS[4][64];
  __shared__ double canddS[4][64];
  int tid = threadIdx.x;
  int b = blockIdx.y;
  int n0 = blockIdx.x * 8;
  for (int i = tid; i < 8 * C; i += 256) {
    int r = i / C, c = i - r * C;
    ctr[r * 128 + c] = xt[((size_t)b * C + c) * NPTS + n0 + r];
  }
  __syncthreads();
  int wave = tid >> 6, wt = tid & 63;
  int r0 = n0 + wave * 2;
  float a0[32], a1[32];
  #pragma unroll
  for (int s = 0; s < 32; ++s) { a0[s] = 0.f; a1[s] = 0.f; }
  const float* xb  = xt + (size_t)b * C * NPTS;
  const float* c0p = ctr + (wave * 2) * 128;
  const float* c1p = c0p + 128;
  for (int c = 0; c < C; ++c) {
    float v0 = c0p[c], v1 = c1p[c];
    const float4* row = (const float4*)(xb + (size_t)c * NPTS) + wt;
    #pragma unroll
    for (int j = 0; j < 8; ++j) {
      float4 xv = row[64 * j];
      a0[j*4+0] = fmaf(v0, xv.x, a0[j*4+0]);
      a0[j*4+1] = fmaf(v0, xv.y, a0[j*4+1]);
      a0[j*4+2] = fmaf(v0, xv.z, a0[j*4+2]);
      a0[j*4+3] = fmaf(v0, xv.w, a0[j*4+3]);
      a1[j*4+0] = fmaf(v1, xv.x, a1[j*4+0]);
      a1[j*4+1] = fmaf(v1, xv.y, a1[j*4+1]);
      a1[j*4+2] = fmaf(v1, xv.z, a1[j*4+2]);
      a1[j*4+3] = fmaf(v1, xv.w, a1[j*4+3]);
    }
  }
  float sqn0 = sq[b * NPTS + r0];
  float sqn1 = sq[b * NPTS + r0 + 1];
  const float4* sqb = (const float4*)(sq + b * NPTS) + wt;
  #pragma unroll
  for (int j = 0; j < 8; ++j) {
    float4 sv = sqb[64 * j];
    a0[j*4+0] = (2.f*a0[j*4+0] - sqn0) - sv.x;
    a0[j*4+1] = (2.f*a0[j*4+1] - sqn0) - sv.y;
    a0[j*4+2] = (2.f*a0[j*4+2] - sqn0) - sv.z;
    a0[j*4+3] = (2.f*a0[j*4+3] - sqn0) - sv.w;
    a1[j*4+0] = (2.f*a1[j*4+0] - sqn1) - sv.x;
    a1[j*4+1] = (2.f*a1[j*4+1] - sqn1) - sv.y;
    a1[j*4+2] = (2.f*a1[j*4+2] - sqn1) - sv.z;
    a1[j*4+3] = (2.f*a1[j*4+3] - sqn1) - sv.w;
  }
  const float* finb = fin + (size_t)b * NPTS * stride;
  row_select(a0, wt, histS[wave], &cntS[wave], candcS[wave], canddS[wave],
             c0p, finb, stride, off, C, idxo + ((size_t)b * NPTS + r0) * KNN);
  row_select(a1, wt, histS[wave], &cntS[wave], candcS[wave], canddS[wave],
             c1p, finb, stride, off, C, idxo + ((size_t)b * NPTS + r0 + 1) * KNN);
}

// ---------------------------------------------------------------------------
// Edge-conv via Z/T decomposition:
//   y[n,k,f] = w1[f]·x_{m(n,k)} + (w2−w1)[f]·x_n = Z[m,f] + T[n,f]

// WC prep: rows 0..F-1 = w1 = w[f][0:C]; rows F..2F-1 = w[f][C:2C]-w[f][0:C]
__global__ void k_wprep(const float* __restrict__ w, float* __restrict__ wc,
                        int C, int F) {
  int i = blockIdx.x * 256 + threadIdx.x;
  if (i >= 2 * F * C) return;
  int n = i / C, c = i - n * C;
  wc[i] = (n < F) ? w[(size_t)n * 2 * C + c]
                  : w[(size_t)(n - F) * 2 * C + C + c] - w[(size_t)(n - F) * 2 * C + c];
}

// ZT(16384 x W2F) = A(16384 x C; row stride lda, col offset off) @ WC^T
template <int C>
__global__ void __launch_bounds__(256) k_zgemm(const float* __restrict__ A, int lda, int off,
                                               const float* __restrict__ WC, int W2F,
                                               float* __restrict__ ZT) {
  __shared__ float As[C][68];
  __shared__ float Ws[C][68];
  int tid = threadIdx.x;
  int m0 = blockIdx.y * 64, f0 = blockIdx.x * 64;
  for (int i = tid; i < 64 * C; i += 256) {
    int r = i / C, c = i - r * C;
    As[c][r] = A[(size_t)(m0 + r) * lda + off + c];
    Ws[c][r] = WC[(size_t)(f0 + r) * C + c];
  }
  __syncthreads();
  int ty = tid >> 4, tx = tid & 15;
  float acc[4][4];
  #pragma unroll
  for (int i = 0; i < 4; ++i)
    #pragma unroll
    for (int j = 0; j < 4; ++j) acc[i][j] = 0.f;
  for (int kk = 0; kk < C; ++kk) {
    float4 a = *(const float4*)&As[kk][ty * 4];
    float4 b = *(const float4*)&Ws[kk][tx * 4];
    acc[0][0] = fmaf(a.x, b.x, acc[0][0]); acc[0][1] = fmaf(a.x, b.y, acc[0][1]);
    acc[0][2] = fmaf(a.x, b.z, acc[0][2]); acc[0][3] = fmaf(a.x, b.w, acc[0][3]);
    acc[1][0] = fmaf(a.y, b.x, acc[1][0]); acc[1][1] = fmaf(a.y, b.y, acc[1][1]);
    acc[1][2] = fmaf(a.y, b.z, acc[1][2]); acc[1][3] = fmaf(a.y, b.w, acc[1][3]);
    acc[2][0] = fmaf(a.z, b.x, acc[2][0]); acc[2][1] = fmaf(a.z, b.y, acc[2][1]);
    acc[2][2] = fmaf(a.z, b.z, acc[2][2]); acc[2][3] = fmaf(a.z, b.w, acc[2][3]);
    acc[3][0] = fmaf(a.w, b.x, acc[3][0]); acc[3][1] = fmaf(a.w, b.y, acc[3][1]);
    acc[3][2] = fmaf(a.w, b.z, acc[3][2]); acc[3][3] = fmaf(a.w, b.w, acc[3][3]);
  }
  #pragma unroll
  for (int i = 0; i < 4; ++i)
    #pragma unroll
    for (int j = 0; j < 4; ++j)
      ZT[(size_t)(m0 + ty * 4 + i) * W2F + f0 + tx * 4 + j] = acc[i][j];
}

// Gather-reduce: per (n,f) max/min over k of Z[m_k,f]+T[n,f], select by
// sign(g[f]) (BN+leaky monotone), write pre-BN into CAT, fp64 stats.
template <int F, int PL, int SP>
__global__ void __launch_bounds__(256) k_gather(const float* __restrict__ ZT, int W2F,
                                                const int* __restrict__ idxb,
                                                const float* __restrict__ g,
                                                float* __restrict__ cat, int catoff,
                                                double* __restrict__ stats) {
  int tid = threadIdx.x;
  int pl = tid / F, f = tid & (F - 1);
  float gg = g[f];
  double s = 0.0, ss = 0.0;
  int nbase = blockIdx.x * (PL * SP) + pl * SP;
  for (int sp = 0; sp < SP; ++sp) {
    int n = nbase + sp;
    int gbase = n & ~(NPTS - 1);
    const int* ip = idxb + n * KNN;
    float T = ZT[(size_t)n * W2F + F + f];
    float mx = -1e30f, mn = 1e30f;
    #pragma unroll
    for (int k = 0; k < KNN; ++k) {
      int m = ip[k];
      float z = ZT[(size_t)(gbase + m) * W2F + f];
      float y = z + T;
      mx = fmaxf(mx, y); mn = fminf(mn, y);
      double yd = (double)y;
      s += yd; ss = fma(yd, yd, ss);
    }
    cat[(size_t)n * 512 + catoff + f] = (gg >= 0.f) ? mx : mn;
  }
  atomicAdd(&stats[f], s);
  atomicAdd(&stats[F + f], ss);
}

// BN + leaky, in place on the CAT slice.
__global__ void k_bn(float* __restrict__ cat, const double* __restrict__ stats,
                     const float* __restrict__ g, const float* __restrict__ bb,
                     int Fbits, int catoff) {
  int i = blockIdx.x * 256 + threadIdx.x;   // over B*N*F, f fastest
  int F = 1 << Fbits;
  int f = i & (F - 1);
  int bn = i >> Fbits;
  const double invCnt = 1.0 / (double)(BATCH * NPTS * KNN);
  double mean = stats[f] * invCnt;
  double ex2  = stats[F + f] * invCnt;
  double var  = ex2 - mean * mean;
  if (var < 0.0) var = 0.0;
  double rs   = rsqrt(var + 1e-5);
  float* p = &cat[(size_t)bn * 512 + catoff + f];
  float y = *p;
  float t = (float)((double)g[f] * ((double)y - mean) * rs + (double)bb[f]);
  *p = (t >= 0.f) ? t : 0.2f * t;
}

// ---------------------------------------------------------------------------
// Final GEMM: CAT(16384x512) @ wf^T(512x1024) -> out(16384x1024).
__global__ void __launch_bounds__(256) k_gemm(const float* __restrict__ A,
                                              const float* __restrict__ Bw,
                                              float* __restrict__ Cc) {
  __shared__ float As[16][68];
  __shared__ float Bs[16][68];
  int tid = threadIdx.x;
  int m0 = blockIdx.y * 64, f0 = blockIdx.x * 64;
  int ty = tid >> 4, tx = tid & 15;
  int lr = tid >> 2;            // 0..63
  int lk = (tid & 3) * 4;       // 0,4,8,12
  float acc[4][4];
  #pragma unroll
  for (int i = 0; i < 4; ++i)
    #pragma unroll
    for (int j = 0; j < 4; ++j) acc[i][j] = 0.f;
  for (int k0 = 0; k0 < 512; k0 += 16) {
    float4 av = *(const float4*)&A [(size_t)(m0 + lr) * 512 + k0 + lk];
    float4 bv = *(const float4*)&Bw[(size_t)(f0 + lr) * 512 + k0 + lk];
    __syncthreads();
    As[lk+0][lr] = av.x; As[lk+1][lr] = av.y; As[lk+2][lr] = av.z; As[lk+3][lr] = av.w;
    Bs[lk+0][lr] = bv.x; Bs[lk+1][lr] = bv.y; Bs[lk+2][lr] = bv.z; Bs[lk+3][lr] = bv.w;
    __syncthreads();
    #pragma unroll
    for (int kk = 0; kk < 16; ++kk) {
      float4 a = *(const float4*)&As[kk][ty * 4];
      float4 b = *(const float4*)&Bs[kk][tx * 4];
      acc[0][0] = fmaf(a.x, b.x, acc[0][0]); acc[0][1] = fmaf(a.x, b.y, acc[0][1]);
      acc[0][2] = fmaf(a.x, b.z, acc[0][2]); acc[0][3] = fmaf(a.x, b.w, acc[0][3]);
      acc[1][0] = fmaf(a.y, b.x, acc[1][0]); acc[1][1] = fmaf(a.y, b.y, acc[1][1]);
      acc[1][2] = fmaf(a.y, b.z, acc[1][2]); acc[1][3] = fmaf(a.y, b.w, acc[1][3]);
      acc[2][0] = fmaf(a.z, b.x, acc[2][0]); acc[2][1] = fmaf(a.z, b.y, acc[2][1]);
      acc[2][2] = fmaf(a.z, b.z, acc[2][2]); acc[2][3] = fmaf(a.z, b.w, acc[2][3]);
      acc[3][0] = fmaf(a.w, b.x, acc[3][0]); acc[3][1] = fmaf(a.w, b.y, acc[3][1]);
      acc[3][2] = fmaf(a.w, b.z, acc[3][2]); acc[3][3] = fmaf(a.w, b.w, acc[3][3]);
    }
  }
  #pragma unroll
  for (int i = 0; i < 4; ++i)
    #pragma unroll
    for (int j = 0; j < 4; ++j)
      Cc[(size_t)(m0 + ty * 4 + i) * 1024 + f0 + tx * 4 + j] = acc[i][j];
}

// Per-channel sum/sumsq (fp64) over 16384 rows of out(16384x1024).
__global__ void k_fstats(const float* __restrict__ y, double* __restrict__ st) {
  int tid = threadIdx.x;
  int r0 = blockIdx.x * 256;
  double s[4] = {0,0,0,0}, ss[4] = {0,0,0,0};
  for (int r = r0; r < r0 + 256; ++r) {
    const float* row = y + (size_t)r * 1024;
    #pragma unroll
    for (int q = 0; q < 4; ++q) {
      double v = (double)row[tid + 256 * q];
      s[q] += v; ss[q] = fma(v, v, ss[q]);
    }
  }
  #pragma unroll
  for (int q = 0; q < 4; ++q) {
    atomicAdd(&st[tid + 256 * q], s[q]);
    atomicAdd(&st[1024 + tid + 256 * q], ss[q]);
  }
}

__global__ void k_fnorm(float* __restrict__ y, const double* __restrict__ st,
                        const float* __restrict__ g, const float* __restrict__ bb) {
  int i = blockIdx.x * 256 + threadIdx.x;
  int f = i & 1023;
  const double invCnt = 1.0 / 16384.0;
  double mean = st[f] * invCnt;
  double ex2  = st[1024 + f] * invCnt;
  double var  = ex2 - mean * mean;
  if (var < 0.0) var = 0.0;
  double rs   = rsqrt(var + 1e-5);
  float v = y[i];
  float t = (float)((double)g[f] * ((double)v - mean) * rs + (double)bb[f]);
  y[i] = (t >= 0.f) ? t : 0.2f * t;
}

// ---------------------------------------------------------------------------
extern "C" void kernel_launch(void* const* d_in, const int* in_sizes, int n_in,
                              void* d_out, int out_size, void* d_ws, size_t ws_size,
                              hipStream_t stream) {
  const float* x  = (const float*)d_in[0];
  const float* W[4]  = {(const float*)d_in[1], (const float*)d_in[4],
                        (const float*)d_in[7], (const float*)d_in[10]};
  const float* G[4]  = {(const float*)d_in[2], (const float*)d_in[5],
                        (const float*)d_in[8], (const float*)d_in[11]};
  const float* Bb[4] = {(const float*)d_in[3], (const float*)d_in[6],
                        (const float*)d_in[9], (const float*)d_in[12]};
  const float* wf = (const float*)d_in[13];
  const float* gf = (const float*)d_in[14];
  const float* bf = (const float*)d_in[15];
  float* out = (float*)d_out;

  // workspace carve: ~77 MB
  float* ws  = (float*)d_ws;
  float* XT  = ws;                 // 8*128*2048      = 2,097,152 f
  float* SQ  = XT + 2097152;       // 8*2048          =    16,384 f
  float* CAT = SQ + 16384;         // 16384*512       = 8,388,608 f
  float* ZT  = CAT + 8388608;      // 16384*512       = 8,388,608 f
  float* WC  = ZT + 8388608;       // 512*128 max     =    65,536 f
  double* ST = (double*)(WC + 65536);      // 2048 doubles
  int*   IDX = (int*)(ST + 2048);  // 16384*20 ints

  const int Cs[4]      = {3, 64, 64, 128};
  const int Fs[4]      = {64, 64, 128, 256};
  const int Fbits[4]   = {6, 6, 7, 8};
  const int offs[4]    = {0, 0, 64, 128};
  const int strides[4] = {3, 512, 512, 512};
  const int catoffs[4] = {0, 64, 128, 256};

  for (int l = 0; l < 4; ++l) {
    const float* fin = (l == 0) ? x : CAT;
    int C = Cs[l], F = Fs[l];
    int W2F = 2 * F;
    k_transpose<<<dim3(BATCH * C * NPTS / 256), 256, 0, stream>>>(fin, strides[l], offs[l], XT, C);
    k_sqnorm<<<dim3(BATCH * NPTS / 256), 256, 0, stream>>>(XT, SQ, C);
    k_knn<<<dim3(NPTS / 8, BATCH), 256, 0, stream>>>(XT, SQ, fin, strides[l], offs[l], IDX, C);
    k_wprep<<<dim3((2 * F * C + 255) / 256), 256, 0, stream>>>(W[l], WC, C, F);
    switch (C) {
      case 3:   k_zgemm<3>  <<<dim3(W2F / 64, 256), 256, 0, stream>>>(fin, strides[l], offs[l], WC, W2F, ZT); break;
      case 64:  k_zgemm<64> <<<dim3(W2F / 64, 256), 256, 0, stream>>>(fin, strides[l], offs[l], WC, W2F, ZT); break;
      default:  k_zgemm<128><<<dim3(W2F / 64, 256), 256, 0, stream>>>(fin, strides[l], offs[l], WC, W2F, ZT); break;
    }
    (void)hipMemsetAsync(ST, 0, 2 * F * sizeof(double), stream);
    switch (F) {
      case 64:  k_gather<64, 4, 16><<<dim3(16384 / 64), 256, 0, stream>>>(ZT, W2F, IDX, G[l], CAT, catoffs[l], ST); break;
      case 128: k_gather<128, 2, 16><<<dim3(16384 / 32), 256, 0, stream>>>(ZT, W2F, IDX, G[l], CAT, catoffs[l], ST); break;
      default:  k_gather<256, 1, 16><<<dim3(16384 / 16), 256, 0, stream>>>(ZT, W2F, IDX, G[l], CAT, catoffs[l], ST); break;
    }
    k_bn<<<dim3(BATCH * NPTS * F / 256), 256, 0, stream>>>(CAT, ST, G[l], Bb[l], Fbits[l], catoffs[l]);
  }

  k_gemm<<<dim3(1024 / 64, 16384 / 64), 256, 0, stream>>>(CAT, wf, out);
  (void)hipMemsetAsync(ST, 0, 2048 * sizeof(double), stream);
  k_fstats<<<dim3(64), 256, 0, stream>>>(out, ST);
  k_fnorm<<<dim3(16384 * 1024 / 256), 256, 0, stream>>>(out, ST, gf, bf);
}